// Round 8
// baseline (1827.816 us; speedup 1.0000x reference)
//
#include <hip/hip_runtime.h>
#include <math.h>

#define BB 2
#define CC 512
#define HH 30
#define WW 40
#define KK 64
#define NPIX (HH*WW)
#define HP 27
#define WP 37
#define NP (HP*WP)
#define LEPS 1e-12f
#define XSTR 300      // LDS row stride (7*40 + 20): c-step 12 banks, b128 conflict-free

// ---------------------------------------------------------------------------
// Kernel 1: per-(b,h) row: channel L2-norm, xn store, logits (K=64) + softmax.
// ---------------------------------------------------------------------------
__global__ __launch_bounds__(512) void k_norm_soft(
    const float* __restrict__ x, const float* __restrict__ convw,
    float* __restrict__ xn, float* __restrict__ soft)
{
  const int h = blockIdx.x, b = blockIdx.y;
  const int t = threadIdx.x;
  __shared__ float xc[64][41];
  __shared__ float cw[64][65];
  __shared__ float Lb[KK][WW + 1];
  __shared__ float psum[12][WW];
  __shared__ float invn[WW];
  __shared__ float mx[WW], Zs[WW];

  const size_t xbase = (size_t)b * CC * NPIX + (size_t)h * WW;

  if (t < 480) {
    const int w = t % 40, part = t / 40;
    float s = 0.f;
    for (int c = part; c < CC; c += 12) {
      const float v = x[xbase + (size_t)c * NPIX + w];
      s = fmaf(v, v, s);
    }
    psum[part][w] = s;
  }
  __syncthreads();
  if (t < 40) {
    float s = 0.f;
    #pragma unroll
    for (int p = 0; p < 12; ++p) s += psum[p][t];
    invn[t] = 1.f / fmaxf(sqrtf(s), LEPS);
  }
  __syncthreads();

  const int k = t & 63, wp = t >> 6;
  float acc[5] = {0.f, 0.f, 0.f, 0.f, 0.f};
  for (int cb = 0; cb < CC; cb += 64) {
    #pragma unroll
    for (int n = 0; n < 5; ++n) {
      const int idx = t + 512 * n;
      const int c = idx / 40, w = idx % 40;
      const float v = x[xbase + (size_t)(cb + c) * NPIX + w] * invn[w];
      xc[c][w] = v;
      xn[xbase + (size_t)(cb + c) * NPIX + w] = v;
    }
    #pragma unroll
    for (int n = 0; n < 8; ++n) {
      const int idx = t + 512 * n;
      const int kk2 = idx >> 6, c2 = idx & 63;
      cw[kk2][c2] = convw[(size_t)kk2 * CC + cb + c2];
    }
    __syncthreads();
    #pragma unroll 1
    for (int c = 0; c < 64; ++c) {
      const float cv = cw[k][c];
      #pragma unroll
      for (int n = 0; n < 5; ++n)
        acc[n] = fmaf(cv, xc[c][wp + 8 * n], acc[n]);
    }
    __syncthreads();
  }
  #pragma unroll
  for (int n = 0; n < 5; ++n) Lb[k][wp + 8 * n] = acc[n];
  __syncthreads();
  if (t < 40) {
    float m = -1e30f;
    for (int kk2 = 0; kk2 < KK; ++kk2) m = fmaxf(m, Lb[kk2][t]);
    float Z = 0.f;
    for (int kk2 = 0; kk2 < KK; ++kk2) Z += expf(Lb[kk2][t] - m);
    mx[t] = m; Zs[t] = Z;
  }
  __syncthreads();
  const size_t sbase = (size_t)b * KK * NPIX + (size_t)h * WW;
  #pragma unroll
  for (int n = 0; n < 5; ++n) {
    const int idx = t + 512 * n;
    const int kk2 = idx / 40, w = idx % 40;
    soft[sbase + (size_t)kk2 * NPIX + w] = expf(Lb[kk2][w] - mx[w]) / Zs[w];
  }
}

// ---------------------------------------------------------------------------
// Kernel G: per-(b,k) global VLAD row, first L2 norm over c.
// ---------------------------------------------------------------------------
__global__ __launch_bounds__(256) void k_global(
    const float* __restrict__ xn, const float* __restrict__ soft,
    const float* __restrict__ cent, float* __restrict__ ghat)
{
  const int k = blockIdx.x, b = blockIdx.y, t = threadIdx.x;
  __shared__ float sb[NPIX];
  __shared__ float red[256];
  const float* srow = soft + ((size_t)b * KK + k) * NPIX;
  for (int i2 = t; i2 < NPIX; i2 += 256) sb[i2] = srow[i2];
  __syncthreads();
  float p = 0.f;
  for (int i2 = t; i2 < NPIX; i2 += 256) p += sb[i2];
  red[t] = p;
  __syncthreads();
  for (int s = 128; s > 0; s >>= 1) { if (t < s) red[t] += red[t + s]; __syncthreads(); }
  const float Sg = red[0];
  __syncthreads();

  const int c0 = t, c1 = t + 256;
  const float* x0 = xn + ((size_t)b * CC + c0) * NPIX;
  const float* x1 = xn + ((size_t)b * CC + c1) * NPIX;
  float a0 = 0.f, a1 = 0.f;
  for (int p4 = 0; p4 < NPIX; p4 += 4) {
    const float4 s4 = *(const float4*)&sb[p4];
    const float4 v0 = *(const float4*)(x0 + p4);
    const float4 v1 = *(const float4*)(x1 + p4);
    a0 = fmaf(s4.x, v0.x, a0); a0 = fmaf(s4.y, v0.y, a0);
    a0 = fmaf(s4.z, v0.z, a0); a0 = fmaf(s4.w, v0.w, a0);
    a1 = fmaf(s4.x, v1.x, a1); a1 = fmaf(s4.y, v1.y, a1);
    a1 = fmaf(s4.z, v1.z, a1); a1 = fmaf(s4.w, v1.w, a1);
  }
  const float g0 = a0 - cent[(size_t)k * CC + c0] * Sg;
  const float g1 = a1 - cent[(size_t)k * CC + c1] * Sg;
  red[t] = g0 * g0 + g1 * g1;
  __syncthreads();
  for (int s = 128; s > 0; s >>= 1) { if (t < s) red[t] += red[t + s]; __syncthreads(); }
  const float inv = 1.f / fmaxf(sqrtf(red[0]), LEPS);
  float* gr = ghat + ((size_t)b * KK + k) * CC;
  gr[c0] = g0 * inv; gr[c1] = g1 * inv;
}

// Global second norm: (a) per-b sum of squares -> inv scale, (b) wide scale.
__global__ __launch_bounds__(256) void k_g2a(
    const float* __restrict__ ghat, float* __restrict__ inv2g)
{
  const int b = blockIdx.x, t = threadIdx.x;
  __shared__ float red[256];
  const float* gb = ghat + (size_t)b * KK * CC;
  float p = 0.f;
  for (int i2 = t; i2 < KK * CC; i2 += 256) { const float v = gb[i2]; p = fmaf(v, v, p); }
  red[t] = p;
  __syncthreads();
  for (int s = 128; s > 0; s >>= 1) { if (t < s) red[t] += red[t + s]; __syncthreads(); }
  if (t == 0) inv2g[b] = 1.f / fmaxf(sqrtf(red[0]), LEPS);
}

__global__ __launch_bounds__(256) void k_g2b(
    const float* __restrict__ ghat, const float* __restrict__ inv2g,
    float* __restrict__ outg)
{
  const int b = blockIdx.y;
  const int u = blockIdx.x * 256 + threadIdx.x;
  if (u < KK * CC)
    outg[(size_t)b * KK * CC + u] = ghat[(size_t)b * KK * CC + u] * inv2g[b];
}

// ---------------------------------------------------------------------------
// Kernel RAW: compute un-normalized raw = 16*box once, store canonical.
// block = (cg 32c, kg 4k, b x 7 i-quarters); t = jq + 10*i2 + 40*c4.
// Lanes 0..39 of a c-group cover 4 rows x 10 j-windows -> each c-row's
// 592B output region is written by ONE 40-lane group, back-to-back stores.
// Compute: aligned ds_read_b128 windows (8 floats -> 4 output j), tile
// 4c x 4k x 4j per thread, barrier-free after staging.
// ---------------------------------------------------------------------------
__global__ __launch_bounds__(320, 3) void k_raw(
    const float* __restrict__ xn, const float* __restrict__ soft,
    const float* __restrict__ cent, float* __restrict__ outr)
{
  const int cg = blockIdx.x;             // 0..15 (32 c)
  const int kg = blockIdx.y;             // 0..15 (4 k)
  const int bz = blockIdx.z;             // b*7 + iq
  const int b = bz / 7, iq = bz % 7;
  const int i0 = iq * 4;
  const int k0 = kg * 4, c0 = cg * 32;
  const int t = threadIdx.x;
  const int jq = t % 10, i2 = (t / 10) & 3, c4 = t / 40;
  const int j0 = jq * 4;
  const int i = i0 + i2;

  __shared__ float xn_l[32 * XSTR];      // 38400 B
  __shared__ float soft_l[4 * XSTR];     //  4800 B
  __shared__ float S_l[4][4][40];        //  2560 B
  __shared__ float cent_l[4][32];        //   512 B

  // stage xn slab: 32 c x 7 rows x 40 w (rows clamped at image edge)
  for (int u = t; u < 2240; u += 320) {
    const int c = u / 70, rem = u - c * 70;
    const int rl = rem / 10, q = rem - rl * 10;
    int row = i0 + rl; if (row > HH - 1) row = HH - 1;
    *(float4*)&xn_l[c * XSTR + rl * 40 + q * 4] =
      *(const float4*)&xn[((size_t)(b * CC + c0 + c)) * NPIX + (size_t)row * 40 + q * 4];
  }
  if (t < 280) {
    const int kk = t / 70, rem = t - kk * 70;
    const int rl = rem / 10, q = rem - rl * 10;
    int row = i0 + rl; if (row > HH - 1) row = HH - 1;
    *(float4*)&soft_l[kk * XSTR + rl * 40 + q * 4] =
      *(const float4*)&soft[((size_t)(b * KK + k0 + kk)) * NPIX + (size_t)row * 40 + q * 4];
  }
  if (t < 128) cent_l[t >> 5][t & 31] = cent[(size_t)(k0 + (t >> 5)) * CC + c0 + (t & 31)];
  __syncthreads();

  // precompute patch sums S_l[k][i2][j] (j>=37 garbage, masked at use)
  if (t < 160) {
    const int kk = t / 40, j = t - (t / 40) * 40;
    #pragma unroll
    for (int ii = 0; ii < 4; ++ii) {
      float s = 0.f;
      #pragma unroll
      for (int r = 0; r < 4; ++r) {
        const int base = kk * XSTR + (ii + r) * 40 + j;
        s += (soft_l[base] + soft_l[base + 1]) + (soft_l[base + 2] + soft_l[base + 3]);
      }
      S_l[kk][ii][j] = s;
    }
  }
  __syncthreads();

  // ---- barrier-free compute ----
  float acc[4][4][4];                    // [cc][kk][jd]
  #pragma unroll
  for (int cc = 0; cc < 4; ++cc)
    #pragma unroll
    for (int kk = 0; kk < 4; ++kk)
      #pragma unroll
      for (int jd = 0; jd < 4; ++jd) acc[cc][kk][jd] = 0.f;

  #pragma unroll
  for (int r = 0; r < 4; ++r) {
    const int rbase = (i2 + r) * 40 + j0;
    float sw[4][8];
    #pragma unroll
    for (int kk = 0; kk < 4; ++kk) {
      const float4 s0 = *(const float4*)&soft_l[kk * XSTR + rbase];
      const float4 s1 = *(const float4*)&soft_l[kk * XSTR + rbase + 4];
      sw[kk][0] = s0.x; sw[kk][1] = s0.y; sw[kk][2] = s0.z; sw[kk][3] = s0.w;
      sw[kk][4] = s1.x; sw[kk][5] = s1.y; sw[kk][6] = s1.z; sw[kk][7] = s1.w;
    }
    #pragma unroll
    for (int cc = 0; cc < 4; ++cc) {
      const int cr = (cc * 8 + c4) * XSTR + rbase;
      const float4 x0 = *(const float4*)&xn_l[cr];
      const float4 x1 = *(const float4*)&xn_l[cr + 4];
      const float xw[8] = {x0.x, x0.y, x0.z, x0.w, x1.x, x1.y, x1.z, x1.w};
      #pragma unroll
      for (int kk = 0; kk < 4; ++kk)
        #pragma unroll
        for (int jd = 0; jd < 4; ++jd) {
          float a = acc[cc][kk][jd];
          a = fmaf(xw[jd + 0], sw[kk][jd + 0], a);
          a = fmaf(xw[jd + 1], sw[kk][jd + 1], a);
          a = fmaf(xw[jd + 2], sw[kk][jd + 2], a);
          a = fmaf(xw[jd + 3], sw[kk][jd + 3], a);
          acc[cc][kk][jd] = a;
        }
    }
  }

  // ---- stores: 40-lane c-groups write contiguous 592B regions ----
  if (i < HP) {
    #pragma unroll
    for (int kk = 0; kk < 4; ++kk) {
      const float4 Sq = *(const float4*)&S_l[kk][i2][j0];
      #pragma unroll
      for (int cc = 0; cc < 4; ++cc) {
        const float cv = cent_l[kk][cc * 8 + c4];
        const size_t idx = ((size_t)((b * KK + k0 + kk) * CC + c0 + cc * 8 + c4)) * NP
                           + (size_t)i * WP + j0;
        outr[idx] = fmaf(-cv, Sq.x, acc[cc][kk][0]);
        if (jq < 9) {
          outr[idx + 1] = fmaf(-cv, Sq.y, acc[cc][kk][1]);
          outr[idx + 2] = fmaf(-cv, Sq.z, acc[cc][kk][2]);
          outr[idx + 3] = fmaf(-cv, Sq.w, acc[cc][kk][3]);
        }
      }
    }
  }
}

// ---------------------------------------------------------------------------
// Kernel NF_a: ssq[bk][p] = sum_c raw^2 — coalesced stream over raw.
// ---------------------------------------------------------------------------
__global__ __launch_bounds__(256) void k_nf_a(
    const float* __restrict__ outr, float* __restrict__ ssq)
{
  const int pb = blockIdx.x;             // 8 strips of 128 p
  const int bk = blockIdx.y;             // 128
  const int t = threadIdx.x;
  const int pl = t & 127, ch = t >> 7;
  const int p = pb * 128 + pl;
  __shared__ float red[2][128];
  float s = 0.f;
  if (p < NP) {
    const float* base = outr + ((size_t)bk * CC + ch * 256) * NP + p;
    #pragma unroll 8
    for (int c = 0; c < 256; ++c) {
      const float v = base[(size_t)c * NP];
      s = fmaf(v, v, s);
    }
  }
  red[ch][pl] = s;
  __syncthreads();
  if (t < 128 && p < NP)
    ssq[(size_t)bk * NP + p] = red[0][pl] + red[1][pl];
}

// ---------------------------------------------------------------------------
// Kernel NF_b: per (b,i): exact per-(b,k,p) scale incl. cross-k second norm.
// ---------------------------------------------------------------------------
__global__ __launch_bounds__(256) void k_nf_b(
    const float* __restrict__ ssq, float* __restrict__ fs)
{
  const int i = blockIdx.x, b = blockIdx.y, t = threadIdx.x;
  __shared__ float sL[64][37];
  __shared__ float inv2[37];
  for (int u = t; u < 64 * 37; u += 256) {
    const int k = u / 37, j = u - (u / 37) * 37;
    sL[k][j] = ssq[((size_t)(b * KK + k)) * NP + (size_t)i * WP + j];
  }
  __syncthreads();
  if (t < 37) {
    float n2s = 0.f;
    for (int k = 0; k < 64; ++k) {
      const float sr = sL[k][t];
      const float iv = 1.f / fmaxf(sqrtf(sr) * 0.0625f, LEPS);
      n2s += sr * (1.f / 256.f) * iv * iv;
    }
    inv2[t] = 1.f / fmaxf(sqrtf(n2s), LEPS);
  }
  __syncthreads();
  for (int u = t; u < 64 * 37; u += 256) {
    const int k = u / 37, j = u - (u / 37) * 37;
    const float sr = sL[k][j];
    const float iv = 1.f / fmaxf(sqrtf(sr) * 0.0625f, LEPS);
    fs[((size_t)(b * KK + k)) * NP + (size_t)i * WP + j] = 0.0625f * iv * inv2[j];
  }
}

// ---------------------------------------------------------------------------
// Kernel SCALE: in-place out[u] *= fs[bk][p]; aligned float4 RMW.
// ---------------------------------------------------------------------------
__global__ __launch_bounds__(256) void k_scale(
    float* __restrict__ outr, const float* __restrict__ fs)
{
  const size_t NV = (size_t)BB * KK * CC * NP / 4;
  const int CPN = CC * NP;
  for (size_t v = (size_t)blockIdx.x * 256 + threadIdx.x; v < NV;
       v += (size_t)gridDim.x * 256) {
    const size_t base = v * 4;
    const int bk = (int)(base / CPN);
    const int rem = (int)(base - (size_t)bk * CPN);
    int p0 = rem % NP;
    const float* fb = fs + (size_t)bk * NP;
    const int p1 = (p0 + 1 == NP) ? 0 : p0 + 1;
    const int p2 = (p1 + 1 == NP) ? 0 : p1 + 1;
    const int p3 = (p2 + 1 == NP) ? 0 : p2 + 1;
    float4 o = *(float4*)&outr[base];
    o.x *= fb[p0]; o.y *= fb[p1]; o.z *= fb[p2]; o.w *= fb[p3];
    *(float4*)&outr[base] = o;
  }
}

// ---------------------------------------------------------------------------
extern "C" void kernel_launch(void* const* d_in, const int* in_sizes, int n_in,
                              void* d_out, int out_size, void* d_ws, size_t ws_size,
                              hipStream_t stream)
{
  const float* x     = (const float*)d_in[0];
  const float* convw = (const float*)d_in[1];
  const float* cent  = (const float*)d_in[2];
  float* out = (float*)d_out;
  float* ws  = (float*)d_ws;

  float* xn    = ws;                                  // B*C*NPIX
  float* soft  = xn    + (size_t)BB * CC * NPIX;      // B*K*NPIX
  float* fs    = soft  + (size_t)BB * KK * NPIX;      // B*K*NP
  float* ghat  = fs    + (size_t)BB * KK * NP;        // B*K*C
  float* ssq   = ghat  + (size_t)BB * KK * CC;        // B*K*NP
  float* inv2g = ssq   + (size_t)BB * KK * NP;        // B

  float* outg = out + (size_t)BB * KK * CC * NP;

  k_norm_soft<<<dim3(HH, BB), 512, 0, stream>>>(x, convw, xn, soft);
  k_raw<<<dim3(16, 16, BB * 7), 320, 0, stream>>>(xn, soft, cent, out);
  k_global<<<dim3(KK, BB), 256, 0, stream>>>(xn, soft, cent, ghat);
  k_g2a<<<dim3(BB), 256, 0, stream>>>(ghat, inv2g);
  k_g2b<<<dim3((KK * CC + 255) / 256, BB), 256, 0, stream>>>(ghat, inv2g, outg);
  k_nf_a<<<dim3(8, BB * KK), 256, 0, stream>>>(out, ssq);
  k_nf_b<<<dim3(HP, BB), 256, 0, stream>>>(ssq, fs);
  k_scale<<<dim3(2048), 256, 0, stream>>>(out, fs);
}

// Round 9
// 710.891 us; speedup vs baseline: 2.5712x; 2.5712x over previous
//
#include <hip/hip_runtime.h>
#include <math.h>

#define BB 2
#define CC 512
#define HH 30
#define WW 40
#define KK 64
#define NPIX (HH*WW)
#define HP 27
#define WP 37
#define NP (HP*WP)
#define LEPS 1e-12f
#define NCG 16        // c-groups (32 c each)
#define XSTR 36       // xn_l px-stride ([px][c] transposed layout)
#define SSTR 284      // soft_l k-stride

// ---------------------------------------------------------------------------
// Kernel 1: per-(b,h) row: channel L2-norm, xn store, logits (K=64) + softmax.
// ---------------------------------------------------------------------------
__global__ __launch_bounds__(512) void k_norm_soft(
    const float* __restrict__ x, const float* __restrict__ convw,
    float* __restrict__ xn, float* __restrict__ soft)
{
  const int h = blockIdx.x, b = blockIdx.y;
  const int t = threadIdx.x;
  __shared__ float xc[64][41];
  __shared__ float cw[64][65];
  __shared__ float Lb[KK][WW + 1];
  __shared__ float psum[12][WW];
  __shared__ float invn[WW];
  __shared__ float mx[WW], Zs[WW];

  const size_t xbase = (size_t)b * CC * NPIX + (size_t)h * WW;

  if (t < 480) {
    const int w = t % 40, part = t / 40;
    float s = 0.f;
    for (int c = part; c < CC; c += 12) {
      const float v = x[xbase + (size_t)c * NPIX + w];
      s = fmaf(v, v, s);
    }
    psum[part][w] = s;
  }
  __syncthreads();
  if (t < 40) {
    float s = 0.f;
    #pragma unroll
    for (int p = 0; p < 12; ++p) s += psum[p][t];
    invn[t] = 1.f / fmaxf(sqrtf(s), LEPS);
  }
  __syncthreads();

  const int k = t & 63, wp = t >> 6;
  float acc[5] = {0.f, 0.f, 0.f, 0.f, 0.f};
  for (int cb = 0; cb < CC; cb += 64) {
    #pragma unroll
    for (int n = 0; n < 5; ++n) {
      const int idx = t + 512 * n;
      const int c = idx / 40, w = idx % 40;
      const float v = x[xbase + (size_t)(cb + c) * NPIX + w] * invn[w];
      xc[c][w] = v;
      xn[xbase + (size_t)(cb + c) * NPIX + w] = v;
    }
    #pragma unroll
    for (int n = 0; n < 8; ++n) {
      const int idx = t + 512 * n;
      const int kk2 = idx >> 6, c2 = idx & 63;
      cw[kk2][c2] = convw[(size_t)kk2 * CC + cb + c2];
    }
    __syncthreads();
    #pragma unroll 1
    for (int c = 0; c < 64; ++c) {
      const float cv = cw[k][c];
      #pragma unroll
      for (int n = 0; n < 5; ++n)
        acc[n] = fmaf(cv, xc[c][wp + 8 * n], acc[n]);
    }
    __syncthreads();
  }
  #pragma unroll
  for (int n = 0; n < 5; ++n) Lb[k][wp + 8 * n] = acc[n];
  __syncthreads();
  if (t < 40) {
    float m = -1e30f;
    for (int kk2 = 0; kk2 < KK; ++kk2) m = fmaxf(m, Lb[kk2][t]);
    float Z = 0.f;
    for (int kk2 = 0; kk2 < KK; ++kk2) Z += expf(Lb[kk2][t] - m);
    mx[t] = m; Zs[t] = Z;
  }
  __syncthreads();
  const size_t sbase = (size_t)b * KK * NPIX + (size_t)h * WW;
  #pragma unroll
  for (int n = 0; n < 5; ++n) {
    const int idx = t + 512 * n;
    const int kk2 = idx / 40, w = idx % 40;
    soft[sbase + (size_t)kk2 * NPIX + w] = expf(Lb[kk2][w] - mx[w]) / Zs[w];
  }
}

// ---------------------------------------------------------------------------
// Kernel G: per-(b,k) global VLAD row, first L2 norm over c.
// ---------------------------------------------------------------------------
__global__ __launch_bounds__(256) void k_global(
    const float* __restrict__ xn, const float* __restrict__ soft,
    const float* __restrict__ cent, float* __restrict__ ghat)
{
  const int k = blockIdx.x, b = blockIdx.y, t = threadIdx.x;
  __shared__ float sb[NPIX];
  __shared__ float red[256];
  const float* srow = soft + ((size_t)b * KK + k) * NPIX;
  for (int i2 = t; i2 < NPIX; i2 += 256) sb[i2] = srow[i2];
  __syncthreads();
  float p = 0.f;
  for (int i2 = t; i2 < NPIX; i2 += 256) p += sb[i2];
  red[t] = p;
  __syncthreads();
  for (int s = 128; s > 0; s >>= 1) { if (t < s) red[t] += red[t + s]; __syncthreads(); }
  const float Sg = red[0];
  __syncthreads();

  const int c0 = t, c1 = t + 256;
  const float* x0 = xn + ((size_t)b * CC + c0) * NPIX;
  const float* x1 = xn + ((size_t)b * CC + c1) * NPIX;
  float a0 = 0.f, a1 = 0.f;
  for (int p4 = 0; p4 < NPIX; p4 += 4) {
    const float4 s4 = *(const float4*)&sb[p4];
    const float4 v0 = *(const float4*)(x0 + p4);
    const float4 v1 = *(const float4*)(x1 + p4);
    a0 = fmaf(s4.x, v0.x, a0); a0 = fmaf(s4.y, v0.y, a0);
    a0 = fmaf(s4.z, v0.z, a0); a0 = fmaf(s4.w, v0.w, a0);
    a1 = fmaf(s4.x, v1.x, a1); a1 = fmaf(s4.y, v1.y, a1);
    a1 = fmaf(s4.z, v1.z, a1); a1 = fmaf(s4.w, v1.w, a1);
  }
  const float g0 = a0 - cent[(size_t)k * CC + c0] * Sg;
  const float g1 = a1 - cent[(size_t)k * CC + c1] * Sg;
  red[t] = g0 * g0 + g1 * g1;
  __syncthreads();
  for (int s = 128; s > 0; s >>= 1) { if (t < s) red[t] += red[t + s]; __syncthreads(); }
  const float inv = 1.f / fmaxf(sqrtf(red[0]), LEPS);
  float* gr = ghat + ((size_t)b * KK + k) * CC;
  gr[c0] = g0 * inv; gr[c1] = g1 * inv;
}

// Global second norm: (a) per-b sum of squares -> inv scale, (b) wide scale.
__global__ __launch_bounds__(256) void k_g2a(
    const float* __restrict__ ghat, float* __restrict__ inv2g)
{
  const int b = blockIdx.x, t = threadIdx.x;
  __shared__ float red[256];
  const float* gb = ghat + (size_t)b * KK * CC;
  float p = 0.f;
  for (int i2 = t; i2 < KK * CC; i2 += 256) { const float v = gb[i2]; p = fmaf(v, v, p); }
  red[t] = p;
  __syncthreads();
  for (int s = 128; s > 0; s >>= 1) { if (t < s) red[t] += red[t + s]; __syncthreads(); }
  if (t == 0) inv2g[b] = 1.f / fmaxf(sqrtf(red[0]), LEPS);
}

__global__ __launch_bounds__(256) void k_g2b(
    const float* __restrict__ ghat, const float* __restrict__ inv2g,
    float* __restrict__ outg)
{
  const int b = blockIdx.y;
  const int u = blockIdx.x * 256 + threadIdx.x;
  if (u < KK * CC)
    outg[(size_t)b * KK * CC + u] = ghat[(size_t)b * KK * CC + u] * inv2g[b];
}

// ---------------------------------------------------------------------------
// Kernel L v9: block = (cg 32c, kg 4k, b x iq of 4 out rows / 7 in rows).
// xn in LDS TRANSPOSED [px][c] (stride 36) -> one ds_read_b128 = 4 c's;
// bank load exactly balanced for both lane maps. Separable box: per input
// row compute PR[k][c] = sum_dx xn*soft (64 FMA), accumulate into the <=4
// output rows whose window contains it (prefix), same for soft row-sums.
// PHASE 0 (map c4=t&7, j=t>>3): ssq partial via 3x shfl_xor -> sp.
// PHASE 1 (map j=t%40, c4=t/40): raw*fs -> out, 40-lane contiguous stores,
// i2 innermost for cache-line combining (R8 lesson).
// ---------------------------------------------------------------------------
template<int PHASE>
__global__ __launch_bounds__(320, 3) void k_local6(
    const float* __restrict__ xn, const float* __restrict__ soft,
    const float* __restrict__ cent, float* __restrict__ sp,
    const float* __restrict__ fs, float* __restrict__ out)
{
  const int cg = blockIdx.x;             // 0..15 (32 c)
  const int kg = blockIdx.y;             // 0..15 (4 k)
  const int bz = blockIdx.z;             // b*7 + iq
  const int b = bz / 7, iq = bz % 7;
  const int i0 = iq * 4;
  const int k0 = kg * 4, c0 = cg * 32;
  const int t = threadIdx.x;
  const int c4 = (PHASE == 0) ? (t & 7) : (t / 40);
  const int j  = (PHASE == 0) ? (t >> 3) : (t % 40);

  __shared__ float xn_l[280 * XSTR + 160];   // [px][c] + tap-overrun margin
  __shared__ float soft_l[4 * SSTR];         // [k][px]
  __shared__ float cent_l[4][32];

  // stage xn transposed: u -> c = u&31, pq = u>>5 (70 float4-quads per c).
  // LDS write banks: (4*px + c) mod 32, c spans 0..31 -> conflict-free.
  for (int u = t; u < 2240; u += 320) {
    const int c = u & 31, pq = u >> 5;
    const int w = (pq % 10) * 4, rl = pq / 10;
    int row = i0 + rl; if (row > HH - 1) row = HH - 1;
    const float4 v = *(const float4*)&xn[((size_t)(b * CC + c0 + c)) * NPIX
                                         + (size_t)row * 40 + w];
    const int px = rl * 40 + w;
    xn_l[(px + 0) * XSTR + c] = v.x;
    xn_l[(px + 1) * XSTR + c] = v.y;
    xn_l[(px + 2) * XSTR + c] = v.z;
    xn_l[(px + 3) * XSTR + c] = v.w;
  }
  if (t < 280) {
    const int kk = t / 70, pq = t % 70;
    const int w = (pq % 10) * 4, rl = pq / 10;
    int row = i0 + rl; if (row > HH - 1) row = HH - 1;
    *(float4*)&soft_l[kk * SSTR + rl * 40 + w] =
      *(const float4*)&soft[((size_t)(b * KK + k0 + kk)) * NPIX
                            + (size_t)row * 40 + w];
  }
  if (t < 128) cent_l[t >> 5][t & 31] = cent[(size_t)(k0 + (t >> 5)) * CC + c0 + (t & 31)];
  __syncthreads();

  // ---- separable compute: 7 input rows -> 4 output rows ----
  float acc[4][4][4];   // [kk][cc][i2]
  float Ssm[4][4];      // [kk][i2]
  #pragma unroll
  for (int kk = 0; kk < 4; ++kk) {
    #pragma unroll
    for (int i2 = 0; i2 < 4; ++i2) Ssm[kk][i2] = 0.f;
    #pragma unroll
    for (int cc = 0; cc < 4; ++cc)
      #pragma unroll
      for (int i2 = 0; i2 < 4; ++i2) acc[kk][cc][i2] = 0.f;
  }

  #pragma unroll
  for (int rl = 0; rl < 7; ++rl) {
    float sv[4][4];                      // [kk][dx]
    #pragma unroll
    for (int kk = 0; kk < 4; ++kk)
      #pragma unroll
      for (int dx = 0; dx < 4; ++dx)
        sv[kk][dx] = soft_l[kk * SSTR + rl * 40 + j + dx];
    float4 xv[4];
    #pragma unroll
    for (int dx = 0; dx < 4; ++dx)
      xv[dx] = *(const float4*)&xn_l[(rl * 40 + j + dx) * XSTR + c4 * 4];

    float SR[4], PR[4][4];               // PR[kk][cc]
    #pragma unroll
    for (int kk = 0; kk < 4; ++kk) {
      SR[kk] = (sv[kk][0] + sv[kk][1]) + (sv[kk][2] + sv[kk][3]);
      #pragma unroll
      for (int cc = 0; cc < 4; ++cc) {
        float p = xv[0][cc] * sv[kk][0];
        p = fmaf(xv[1][cc], sv[kk][1], p);
        p = fmaf(xv[2][cc], sv[kk][2], p);
        p = fmaf(xv[3][cc], sv[kk][3], p);
        PR[kk][cc] = p;
      }
    }
    #pragma unroll
    for (int i2 = 0; i2 < 4; ++i2) {
      if (i2 <= rl && rl <= i2 + 3) {    // compile-time predicate
        #pragma unroll
        for (int kk = 0; kk < 4; ++kk) {
          Ssm[kk][i2] += SR[kk];
          #pragma unroll
          for (int cc = 0; cc < 4; ++cc)
            acc[kk][cc][i2] += PR[kk][cc];
        }
      }
    }
  }

  // ---- epilogue ----
  if (PHASE == 0) {
    #pragma unroll
    for (int kk = 0; kk < 4; ++kk)
      #pragma unroll
      for (int i2 = 0; i2 < 4; ++i2) {
        const int i = i0 + i2;
        float s = 0.f;
        #pragma unroll
        for (int cc = 0; cc < 4; ++cc) {
          const float raw = fmaf(-cent_l[kk][c4 * 4 + cc], Ssm[kk][i2], acc[kk][cc][i2]);
          s = fmaf(raw, raw, s);
        }
        s += __shfl_xor(s, 1, 64);
        s += __shfl_xor(s, 2, 64);
        s += __shfl_xor(s, 4, 64);
        if (c4 == 0 && i < HP && j < WP)
          sp[(((size_t)(b * KK + k0 + kk)) * NCG + cg) * NP + (size_t)i * WP + j] = s;
      }
  } else if (j < WP) {
    #pragma unroll
    for (int kk = 0; kk < 4; ++kk) {
      const size_t bk = (size_t)(b * KK + k0 + kk);
      float fsv[4];
      #pragma unroll
      for (int i2 = 0; i2 < 4; ++i2)
        fsv[i2] = (i0 + i2 < HP) ? fs[bk * NP + (size_t)(i0 + i2) * WP + j] : 0.f;
      #pragma unroll
      for (int cc = 0; cc < 4; ++cc) {
        const float cv = cent_l[kk][c4 * 4 + cc];
        const size_t obase = (bk * CC + c0 + c4 * 4 + cc) * NP + (size_t)i0 * WP + j;
        #pragma unroll
        for (int i2 = 0; i2 < 4; ++i2) {
          if (i0 + i2 < HP) {
            const float raw = fmaf(-cv, Ssm[kk][i2], acc[kk][cc][i2]);
            out[obase + (size_t)i2 * WP] = raw * fsv[i2];
          }
        }
      }
    }
  }
}

// ---------------------------------------------------------------------------
// Kernel NF: per (b, 4 pixels): sum the 16 c-group partials, build the exact
// per-(b,k,p) scale with a 64-way LDS reduce for the cross-k second norm.
// ---------------------------------------------------------------------------
__global__ __launch_bounds__(256) void k_nf(
    const float* __restrict__ sp, float* __restrict__ fs)
{
  const int b = blockIdx.y, t = threadIdx.x;
  const int k = t >> 2, dp = t & 3;
  const int p = blockIdx.x * 4 + dp;
  __shared__ float red[64][4];
  __shared__ float inv2s[4];
  const bool ok = p < NP;
  float sr = 0.f;
  if (ok) {
    #pragma unroll
    for (int g = 0; g < NCG; ++g)
      sr += sp[(((size_t)(b * KK + k)) * NCG + g) * NP + p];
  }
  const float iv = 1.f / fmaxf(sqrtf(sr) * 0.0625f, LEPS);
  red[k][dp] = sr * (1.f / 256.f) * iv * iv;
  __syncthreads();
  if (t < 4) {
    float s = 0.f;
    #pragma unroll
    for (int kk = 0; kk < 64; ++kk) s += red[kk][t];
    inv2s[t] = 1.f / fmaxf(sqrtf(s), LEPS);
  }
  __syncthreads();
  if (ok)
    fs[((size_t)(b * KK + k)) * NP + p] = 0.0625f * iv * inv2s[dp];
}

// ---------------------------------------------------------------------------
extern "C" void kernel_launch(void* const* d_in, const int* in_sizes, int n_in,
                              void* d_out, int out_size, void* d_ws, size_t ws_size,
                              hipStream_t stream)
{
  const float* x     = (const float*)d_in[0];
  const float* convw = (const float*)d_in[1];
  const float* cent  = (const float*)d_in[2];
  float* out = (float*)d_out;
  float* ws  = (float*)d_ws;

  float* xn    = ws;                                  // B*C*NPIX
  float* soft  = xn    + (size_t)BB * CC * NPIX;      // B*K*NPIX
  float* fs    = soft  + (size_t)BB * KK * NPIX;      // B*K*NP
  float* ghat  = fs    + (size_t)BB * KK * NP;        // B*K*C
  float* sp    = ghat  + (size_t)BB * KK * CC;        // B*K*NCG*NP
  float* inv2g = sp    + (size_t)BB * KK * NCG * NP;  // B

  float* outg = out + (size_t)BB * KK * CC * NP;

  k_norm_soft<<<dim3(HH, BB), 512, 0, stream>>>(x, convw, xn, soft);
  k_global<<<dim3(KK, BB), 256, 0, stream>>>(xn, soft, cent, ghat);
  k_g2a<<<dim3(BB), 256, 0, stream>>>(ghat, inv2g);
  k_g2b<<<dim3((KK * CC + 255) / 256, BB), 256, 0, stream>>>(ghat, inv2g, outg);
  k_local6<0><<<dim3(NCG, KK / 4, BB * 7), 320, 0, stream>>>(xn, soft, cent, sp, fs, out);
  k_nf<<<dim3((NP + 3) / 4, BB), 256, 0, stream>>>(sp, fs);
  k_local6<1><<<dim3(NCG, KK / 4, BB * 7), 320, 0, stream>>>(xn, soft, cent, sp, fs, out);
}